// Round 1
// baseline (198608.289 us; speedup 1.0000x reference)
//
#include <hip/hip_runtime.h>
#include <hip/hip_bf16.h>

#define NWG 32
#define TSEQ 512
#define JW 16          // h-columns per WG
#define HH 512
#define II 1024
#define GSTRIDE 1280   // padded row stride of G (floats/bf16 elements)

// workspace byte offsets
#define OFF_CNT    0u
#define OFF_HBUF   1024u                       // 2*512 f32
#define OFF_CBUF   (OFF_HBUF + 2u*HH*4u)       // 2*512 f32
#define OFF_RPP    (OFF_CBUF + 2u*HH*4u)       // 2*32*104 f32
#define OFF_WPL    (OFF_RPP + 2u*NWG*104u*4u)  // 2*104 f32
#define OFF_WSTACK (1u<<20)                    // 1025*1280 f32 ~ 5.25 MB
#define OFF_G      (16u<<20)                   // N*1280 bf16 ~ 84 MB

__device__ __forceinline__ float bf2f(__hip_bfloat16 x){ return __bfloat162float(x); }

__device__ __forceinline__ float red32(float v){
  v += __shfl_xor(v, 16); v += __shfl_xor(v, 8); v += __shfl_xor(v, 4);
  v += __shfl_xor(v, 2);  v += __shfl_xor(v, 1);
  return v;
}

__device__ __forceinline__ void grid_barrier(unsigned int* cnt, unsigned int target){
  __syncthreads();
  if (threadIdx.x == 0) {
    __threadfence();
    __hip_atomic_fetch_add(cnt, 1u, __ATOMIC_ACQ_REL, __HIP_MEMORY_SCOPE_AGENT);
    while (__hip_atomic_load(cnt, __ATOMIC_ACQUIRE, __HIP_MEMORY_SCOPE_AGENT) < target) {
      __builtin_amdgcn_s_sleep(1);
    }
    __threadfence();
  }
  __syncthreads();
}

// ---------------- pack: Wstack[1025][1280], row 1024 = bias row ----------------
__global__ void pack_kernel(const float* __restrict__ Wxh, const float* __restrict__ bh,
                            const float* __restrict__ Wc,  const float* __restrict__ bc,
                            const float* __restrict__ Wrp, const float* __restrict__ brp,
                            const float* __restrict__ Wwp, const float* __restrict__ bwp,
                            const float* __restrict__ Wrg, const float* __restrict__ brg,
                            const float* __restrict__ Wwg, const float* __restrict__ bwg,
                            float* __restrict__ Wstack)
{
  int n = blockIdx.x*256 + threadIdx.x;
  int k = blockIdx.y;
  if (n >= GSTRIDE) return;
  float v = 0.f;
  if (k < II) {
    if (n < 512)       v = Wxh[k*512 + n];
    else if (n < 1024) v = Wc[k*512 + (n-512)];
    else if (n < 1124) v = Wrp[k*100 + (n-1024)];
    else if (n < 1224) v = Wwp[k*100 + (n-1124)];
    else if (n == 1224) v = Wrg[k];
    else if (n == 1225) v = Wwg[k];
  } else {
    if (n < 512)       v = bh[n];
    else if (n < 1024) v = bc[n-512];
    else if (n < 1124) v = brp[n-1024];
    else if (n < 1224) v = bwp[n-1124];
    else if (n == 1224) v = brg[0];
    else if (n == 1225) v = bwg[0];
  }
  Wstack[k*GSTRIDE + n] = v;
}

// ---------------- GEMM: G = X(32768x1024) @ Wstack(1024x1280) + bias, bf16 out ----------------
__global__ __launch_bounds__(256) void gemm_kernel(const float* __restrict__ X,
                                                   const float* __restrict__ Wstack,
                                                   __hip_bfloat16* __restrict__ G)
{
  __shared__ float As[16][68];
  __shared__ float Bs[16][64];
  const int tid = threadIdx.x;
  const int row0 = blockIdx.y*64, col0 = blockIdx.x*64;
  const int ty = tid>>4, tx = tid&15;
  const int amm = tid>>2, akk = (tid&3)<<2;
  const int bkk = tid>>4, bnn = (tid&15)<<2;
  float acc[4][4] = {{0.f}};
  for (int k0 = 0; k0 < II; k0 += 16) {
    float4 av = *(const float4*)(X + (size_t)(row0+amm)*II + k0 + akk);
    float4 bv = *(const float4*)(Wstack + (size_t)(k0+bkk)*GSTRIDE + col0 + bnn);
    __syncthreads();
    As[akk+0][amm]=av.x; As[akk+1][amm]=av.y; As[akk+2][amm]=av.z; As[akk+3][amm]=av.w;
    *(float4*)&Bs[bkk][bnn] = bv;
    __syncthreads();
#pragma unroll
    for (int kk=0; kk<16; kk++){
      float4 a = *(float4*)&As[kk][ty<<2];
      float4 b = *(float4*)&Bs[kk][tx<<2];
      acc[0][0] += a.x*b.x; acc[0][1] += a.x*b.y; acc[0][2] += a.x*b.z; acc[0][3] += a.x*b.w;
      acc[1][0] += a.y*b.x; acc[1][1] += a.y*b.y; acc[1][2] += a.y*b.z; acc[1][3] += a.y*b.w;
      acc[2][0] += a.z*b.x; acc[2][1] += a.z*b.y; acc[2][2] += a.z*b.z; acc[2][3] += a.z*b.w;
      acc[3][0] += a.w*b.x; acc[3][1] += a.w*b.y; acc[3][2] += a.w*b.z; acc[3][3] += a.w*b.w;
    }
  }
#pragma unroll
  for (int i2=0;i2<4;i2++){
    int r = row0 + (ty<<2) + i2;
#pragma unroll
    for (int j2=0;j2<4;j2++){
      int cidx = col0 + (tx<<2) + j2;
      float v = acc[i2][j2] + Wstack[(size_t)II*GSTRIDE + cidx];
      G[(size_t)r*GSTRIDE + cidx] = __float2bfloat16(v);
    }
  }
}

// ---------------- persistent sequential kernel ----------------
// State eliminated: mem replaced by memW = mem @ Wrh (exact algebra).
// One global barrier per step; double-buffered publish arrays.
__global__ __launch_bounds__(TSEQ) void seq_kernel(
    const float* __restrict__ Wc,  const float* __restrict__ Wwg,
    const float* __restrict__ Wwp, const float* __restrict__ Wrg,
    const float* __restrict__ Wrp, const float* __restrict__ Wrh,
    const float* __restrict__ Whh,
    const __hip_bfloat16* __restrict__ G,
    float* __restrict__ out,
    unsigned int* cnt, float* hb, float* cb, float* rpp, float* wpl, int N)
{
  const int w = blockIdx.x;
  const int t = threadIdx.x;
  const int j = t >> 5;        // 0..15 local column
  const int l = t & 31;
  const int jg = w*JW + j;     // global h column

  __shared__ float hp[HH], cp[HH];
  __shared__ float ht[JW], zhh[JW], zc[JW], cwv[JW];
  __shared__ float rplog[104], e_ar[104], awlog[104], aw_n[104];
  __shared__ float part6[4][104];
  __shared__ float part2[4][128];
  __shared__ float memW[JW][104];
  __shared__ float Wrp_sl[JW][104];
  __shared__ float Wwp_sl[4][HH];
  __shared__ float scal[4];

  // register-resident column slices: Whh[:,jg], Wc_h[:,jg], Wrh[:,jg]
  float whh_r[16], wch_r[16], wrh_r[16];
#pragma unroll
  for (int i=0;i<16;i++){
    int k = i*32 + l;
    whh_r[i] = Whh[(size_t)k*HH + jg];
    wch_r[i] = Wc[(size_t)(II+k)*HH + jg];
    wrh_r[i] = Wrh[(size_t)k*HH + jg];
  }
  for (int idx=t; idx<JW*104; idx+=TSEQ){
    int kl = idx/104, m = idx - kl*104;
    int kgl = II + w*JW + kl;
    float v = 0.f;
    if (m < 100) v = Wrp[(size_t)kgl*100 + m];
    else if (m == 100) v = Wrg[kgl];
    Wrp_sl[kl][m] = v;
    memW[kl][m] = 0.f;   // same index space (JW x 104)
  }
  for (int idx=t; idx<4*HH; idx+=TSEQ){
    int ci = idx>>9, k = idx&511;
    int cg = ci*32 + w;
    float v = 0.f;
    if (cg < 100) v = Wwp[(size_t)(II+k)*100 + cg];
    else if (cg == 100) v = Wwg[II+k];
    Wwp_sl[ci][k] = v;
  }
  __syncthreads();

  // ---- phase 0: h0 = relu(B0), c0 = relu(A0); memW=0 => rW=0 regardless of ar/go ----
  if (t < JW) {
    float hv = fmaxf(0.f, bf2f(G[(size_t)0*GSTRIDE + w*JW + t]));
    float cv = fmaxf(0.f, bf2f(G[(size_t)0*GSTRIDE + 512 + w*JW + t]));
    ht[t] = hv;
    hb[0*HH + w*JW + t] = hv;
    cb[0*HH + w*JW + t] = cv;
    out[(size_t)0*HH + w*JW + t] = hv;
  }
  if (t < 4) {                 // wp logits for step 0 use h_{-1}=0 -> publish zeros
    int cg = t*32 + w;
    if (cg < 101) wpl[0*104 + cg] = 0.f;
  }
  __syncthreads();
  if (t < 404) {               // rp partials for step 1 from local h0 slice
    int m = t % 101, q = t / 101;
    float s = 0.f;
#pragma unroll
    for (int ii=0; ii<4; ii++) s += ht[q*4+ii] * Wrp_sl[q*4+ii][m];
    part6[q][m] = s;
  }
  __syncthreads();
  if (t < 101)
    rpp[(size_t)(0*NWG + w)*104 + t] = part6[0][t]+part6[1][t]+part6[2][t]+part6[3][t];
  grid_barrier(cnt, NWG*1u);

  for (int step=1; step<N; ++step) {
    const int cur = step & 1, prv = cur ^ 1;
    // (1) read previous phase's publishes
    hp[t] = hb[prv*HH + t];
    cp[t] = cb[prv*HH + t];
    if (t < 404) {
      int m = t % 101, q = t / 101;
      const float* base = rpp + (size_t)(prv*NWG)*104 + m;
      float s0 = base[(q*8+0)*104], s1 = base[(q*8+1)*104];
      float s2 = base[(q*8+2)*104], s3 = base[(q*8+3)*104];
      float s4 = base[(q*8+4)*104], s5 = base[(q*8+5)*104];
      float s6 = base[(q*8+6)*104], s7 = base[(q*8+7)*104];
      part6[q][m] = ((s0+s1)+(s2+s3)) + ((s4+s5)+(s6+s7));
    } else if (t < 505) {
      awlog[t - 404] = wpl[prv*104 + (t-404)];
    }
    __syncthreads();
    // (2) finalize logits (add x-parts from G)
    if (t < 101) {
      float s = part6[0][t]+part6[1][t]+part6[2][t]+part6[3][t];
      s += bf2f(G[(size_t)step*GSTRIDE + (t<100 ? 1024+t : 1224)]);
      rplog[t] = s;
    } else if (t >= 128 && t < 229) {
      int m = t - 128;
      awlog[m] += bf2f(G[(size_t)(step-1)*GSTRIDE + (m<100 ? 1124+m : 1225)]);
    }
    __syncthreads();
    // (3) register matvecs (Whh, Wc_h with h; Wrh with c) + wp partial dots
    float ph=0.f, pc=0.f, pw=0.f;
#pragma unroll
    for (int i=0;i<16;i++){
      float hv = hp[i*32+l], cv2 = cp[i*32+l];
      ph += whh_r[i]*hv;
      pc += wch_r[i]*hv;
      pw += wrh_r[i]*cv2;
    }
    ph = red32(ph); pc = red32(pc); pw = red32(pw);
    if (l == 0) { zhh[j]=ph; zc[j]=pc; cwv[j]=pw; }
    {
      int ci = t >> 7, li = t & 127;
      float s = 0.f;
#pragma unroll
      for (int ii=0; ii<4; ii++) s += hp[li + 128*ii] * Wwp_sl[ci][li + 128*ii];
      part2[ci][li] = s;
    }
    __syncthreads();
    // (4) softmaxes (waves 0,1) + wp logit publish (waves 2..5)
    {
      const int wv = t >> 6;
      if (wv == 0) {
        float v0 = rplog[t];
        float v1 = (t+64 < 100) ? rplog[t+64] : -1e30f;
        float mx = fmaxf(v0, v1);
#pragma unroll
        for (int off=32; off>=1; off>>=1) mx = fmaxf(mx, __shfl_xor(mx, off));
        float e0 = __expf(v0 - mx);
        float e1 = (t+64 < 100) ? __expf(v1 - mx) : 0.f;
        e_ar[t] = e0;
        if (t + 64 < 104) e_ar[t+64] = e1;
        float s = e0 + e1;
#pragma unroll
        for (int off=32; off>=1; off>>=1) s += __shfl_xor(s, off);
        if (t == 0) {
          float go = 1.f/(1.f+__expf(-rplog[100]));
          scal[0] = go / s;
        }
      } else if (wv == 1) {
        int m0 = t - 64;
        float v0 = awlog[m0];
        float v1 = (m0+64 < 100) ? awlog[m0+64] : -1e30f;
        float mx = fmaxf(v0, v1);
#pragma unroll
        for (int off=32; off>=1; off>>=1) mx = fmaxf(mx, __shfl_xor(mx, off));
        float e0 = __expf(v0 - mx);
        float e1 = (m0+64 < 100) ? __expf(v1 - mx) : 0.f;
        float s = e0 + e1;
#pragma unroll
        for (int off=32; off>=1; off>>=1) s += __shfl_xor(s, off);
        aw_n[m0] = e0 / s;
        if (m0+64 < 100) aw_n[m0+64] = e1 / s;
        if (m0 == 0) scal[1] = 1.f/(1.f+__expf(-awlog[100]));
      } else if (wv >= 2 && wv < 6) {
        int ci = wv - 2, ln = t & 63;
        float s = part2[ci][ln] + part2[ci][ln+64];
#pragma unroll
        for (int off=32; off>=1; off>>=1) s += __shfl_xor(s, off);
        if (ln == 0) {
          int cg = ci*32 + w;
          if (cg < 101) wpl[cur*104 + cg] = s;
        }
      }
    }
    __syncthreads();
    // (5) memW update (with aw_{t-1}, gw_{t-1}, cW_{t-1}) fused with rW accumulation
    {
      float gws = scal[1], gosum = scal[0], cwj = cwv[j];
      float rwp = 0.f;
#pragma unroll
      for (int q=0; q<4; q++){
        int m = l + 32*q;
        if (m < 100) {
          float a = aw_n[m];
          float mv = memW[j][m];
          mv = (1.f - a)*mv + gws*a*cwj;
          memW[j][m] = mv;
          rwp += e_ar[m]*mv;
        }
      }
      rwp = red32(rwp);
      if (l == 0) {
        float hv = fmaxf(0.f, bf2f(G[(size_t)step*GSTRIDE + jg]) + zhh[j] + gosum*rwp);
        float cv = fmaxf(0.f, bf2f(G[(size_t)step*GSTRIDE + 512 + jg]) + zc[j]);
        ht[j] = hv;
        out[(size_t)step*HH + jg] = hv;
        hb[cur*HH + jg] = hv;
        cb[cur*HH + jg] = cv;
      }
    }
    __syncthreads();
    // (6) rp partials for next step + barrier
    if (step + 1 < N) {
      if (t < 404) {
        int m = t % 101, q = t / 101;
        float s = 0.f;
#pragma unroll
        for (int ii=0; ii<4; ii++) s += ht[q*4+ii]*Wrp_sl[q*4+ii][m];
        part6[q][m] = s;
      }
      __syncthreads();
      if (t < 101)
        rpp[(size_t)(cur*NWG + w)*104 + t] = part6[0][t]+part6[1][t]+part6[2][t]+part6[3][t];
      grid_barrier(cnt, NWG*(unsigned)(step+1));
    }
  }
}

extern "C" void kernel_launch(void* const* d_in, const int* in_sizes, int n_in,
                              void* d_out, int out_size, void* d_ws, size_t ws_size,
                              hipStream_t stream) {
  const float* X   = (const float*)d_in[0];
  const float* Wc  = (const float*)d_in[1];
  const float* bc  = (const float*)d_in[2];
  const float* Wwg = (const float*)d_in[3];
  const float* bwg = (const float*)d_in[4];
  const float* Wwp = (const float*)d_in[5];
  const float* bwp = (const float*)d_in[6];
  const float* Wrg = (const float*)d_in[7];
  const float* brg = (const float*)d_in[8];
  const float* Wrp = (const float*)d_in[9];
  const float* brp = (const float*)d_in[10];
  const float* Wxh = (const float*)d_in[11];
  const float* Wrh = (const float*)d_in[12];
  const float* Whh = (const float*)d_in[13];
  const float* bh  = (const float*)d_in[14];

  const int N = in_sizes[0] / II;   // 32768

  char* ws = (char*)d_ws;
  unsigned int* cnt = (unsigned int*)(ws + OFF_CNT);
  float* hb  = (float*)(ws + OFF_HBUF);
  float* cb  = (float*)(ws + OFF_CBUF);
  float* rpp = (float*)(ws + OFF_RPP);
  float* wpl = (float*)(ws + OFF_WPL);
  float* Wstack = (float*)(ws + OFF_WSTACK);
  __hip_bfloat16* G = (__hip_bfloat16*)(ws + OFF_G);
  float* out = (float*)d_out;

  // zero the barrier counter (ws is poisoned 0xAA before every timed launch)
  hipMemsetAsync(ws, 0, 1024, stream);

  pack_kernel<<<dim3(GSTRIDE/256, II+1), 256, 0, stream>>>(
      Wxh, bh, Wc, bc, Wrp, brp, Wwp, bwp, Wrg, brg, Wwg, bwg, Wstack);

  gemm_kernel<<<dim3(GSTRIDE/64, N/64), 256, 0, stream>>>(X, Wstack, G);

  seq_kernel<<<NWG, TSEQ, 0, stream>>>(
      Wc, Wwg, Wwp, Wrg, Wrp, Wrh, Whh, G, out,
      cnt, hb, cb, rpp, wpl, N);
}

// Round 2
// 169790.991 us; speedup vs baseline: 1.1697x; 1.1697x over previous
//
#include <hip/hip_runtime.h>
#include <hip/hip_bf16.h>

#define NWG 32
#define TSEQ 512
#define JW 16          // h-columns per WG
#define HH 512
#define II 1024
#define GSTRIDE 1280   // padded row stride of G (floats/bf16 elements)

// workspace byte offsets
#define OFF_CNT    0u
#define OFF_HBUF   1024u                       // 2*512 f32
#define OFF_CBUF   (OFF_HBUF + 2u*HH*4u)       // 2*512 f32
#define OFF_RPP    (OFF_CBUF + 2u*HH*4u)       // 2*32*104 f32
#define OFF_WPL    (OFF_RPP + 2u*NWG*104u*4u)  // 2*104 f32
#define OFF_WSTACK (1u<<20)                    // 1025*1280 f32 ~ 5.25 MB
#define OFF_G      (16u<<20)                   // N*1280 bf16 ~ 84 MB

__device__ __forceinline__ float bf2f(__hip_bfloat16 x){ return __bfloat162float(x); }

// ---- cross-WG communication: relaxed agent-scope atomics (sc1 cache-bypass,
// coherent at Infinity Cache, NO wbl2/inv fences) ----
__device__ __forceinline__ void gstore(float* p, float v){
  __hip_atomic_store(p, v, __ATOMIC_RELAXED, __HIP_MEMORY_SCOPE_AGENT);
}
__device__ __forceinline__ float gload(const float* p){
  return __hip_atomic_load(p, __ATOMIC_RELAXED, __HIP_MEMORY_SCOPE_AGENT);
}

__device__ __forceinline__ float red32(float v){
  v += __shfl_xor(v, 16); v += __shfl_xor(v, 8); v += __shfl_xor(v, 4);
  v += __shfl_xor(v, 2);  v += __shfl_xor(v, 1);
  return v;
}

// Fence-free barrier: __syncthreads() drains each wave's vmcnt (sc1 stores are
// at the coherence point once acked); counter add + polls are relaxed sc1 ops.
__device__ __forceinline__ void grid_barrier(unsigned int* cnt, unsigned int target){
  __syncthreads();
  if (threadIdx.x == 0) {
    __builtin_amdgcn_s_waitcnt(0);   // belt-and-suspenders: drain own queue
    __hip_atomic_fetch_add(cnt, 1u, __ATOMIC_RELAXED, __HIP_MEMORY_SCOPE_AGENT);
    while (__hip_atomic_load(cnt, __ATOMIC_RELAXED, __HIP_MEMORY_SCOPE_AGENT) < target) {
    }
  }
  __syncthreads();
}

// ---------------- pack: Wstack[1025][1280], row 1024 = bias row ----------------
__global__ void pack_kernel(const float* __restrict__ Wxh, const float* __restrict__ bh,
                            const float* __restrict__ Wc,  const float* __restrict__ bc,
                            const float* __restrict__ Wrp, const float* __restrict__ brp,
                            const float* __restrict__ Wwp, const float* __restrict__ bwp,
                            const float* __restrict__ Wrg, const float* __restrict__ brg,
                            const float* __restrict__ Wwg, const float* __restrict__ bwg,
                            float* __restrict__ Wstack)
{
  int n = blockIdx.x*256 + threadIdx.x;
  int k = blockIdx.y;
  if (n >= GSTRIDE) return;
  float v = 0.f;
  if (k < II) {
    if (n < 512)       v = Wxh[k*512 + n];
    else if (n < 1024) v = Wc[k*512 + (n-512)];
    else if (n < 1124) v = Wrp[k*100 + (n-1024)];
    else if (n < 1224) v = Wwp[k*100 + (n-1124)];
    else if (n == 1224) v = Wrg[k];
    else if (n == 1225) v = Wwg[k];
  } else {
    if (n < 512)       v = bh[n];
    else if (n < 1024) v = bc[n-512];
    else if (n < 1124) v = brp[n-1024];
    else if (n < 1224) v = bwp[n-1124];
    else if (n == 1224) v = brg[0];
    else if (n == 1225) v = bwg[0];
  }
  Wstack[k*GSTRIDE + n] = v;
}

// ---------------- GEMM: G = X(32768x1024) @ Wstack(1024x1280) + bias, bf16 out ----------------
__global__ __launch_bounds__(256) void gemm_kernel(const float* __restrict__ X,
                                                   const float* __restrict__ Wstack,
                                                   __hip_bfloat16* __restrict__ G)
{
  __shared__ float As[16][68];
  __shared__ float Bs[16][64];
  const int tid = threadIdx.x;
  const int row0 = blockIdx.y*64, col0 = blockIdx.x*64;
  const int ty = tid>>4, tx = tid&15;
  const int amm = tid>>2, akk = (tid&3)<<2;
  const int bkk = tid>>4, bnn = (tid&15)<<2;
  float acc[4][4] = {{0.f}};
  for (int k0 = 0; k0 < II; k0 += 16) {
    float4 av = *(const float4*)(X + (size_t)(row0+amm)*II + k0 + akk);
    float4 bv = *(const float4*)(Wstack + (size_t)(k0+bkk)*GSTRIDE + col0 + bnn);
    __syncthreads();
    As[akk+0][amm]=av.x; As[akk+1][amm]=av.y; As[akk+2][amm]=av.z; As[akk+3][amm]=av.w;
    *(float4*)&Bs[bkk][bnn] = bv;
    __syncthreads();
#pragma unroll
    for (int kk=0; kk<16; kk++){
      float4 a = *(float4*)&As[kk][ty<<2];
      float4 b = *(float4*)&Bs[kk][tx<<2];
      acc[0][0] += a.x*b.x; acc[0][1] += a.x*b.y; acc[0][2] += a.x*b.z; acc[0][3] += a.x*b.w;
      acc[1][0] += a.y*b.x; acc[1][1] += a.y*b.y; acc[1][2] += a.y*b.z; acc[1][3] += a.y*b.w;
      acc[2][0] += a.z*b.x; acc[2][1] += a.z*b.y; acc[2][2] += a.z*b.z; acc[2][3] += a.z*b.w;
      acc[3][0] += a.w*b.x; acc[3][1] += a.w*b.y; acc[3][2] += a.w*b.z; acc[3][3] += a.w*b.w;
    }
  }
#pragma unroll
  for (int i2=0;i2<4;i2++){
    int r = row0 + (ty<<2) + i2;
#pragma unroll
    for (int j2=0;j2<4;j2++){
      int cidx = col0 + (tx<<2) + j2;
      float v = acc[i2][j2] + Wstack[(size_t)II*GSTRIDE + cidx];
      G[(size_t)r*GSTRIDE + cidx] = __float2bfloat16(v);
    }
  }
}

// ---------------- persistent sequential kernel ----------------
// State eliminated: mem replaced by memW = mem @ Wrh (exact algebra).
// One global barrier per step; double-buffered publish arrays; all cross-WG
// traffic via relaxed sc1 atomics (no cache-maintenance fences anywhere).
__global__ __launch_bounds__(TSEQ) void seq_kernel(
    const float* __restrict__ Wc,  const float* __restrict__ Wwg,
    const float* __restrict__ Wwp, const float* __restrict__ Wrg,
    const float* __restrict__ Wrp, const float* __restrict__ Wrh,
    const float* __restrict__ Whh,
    const __hip_bfloat16* __restrict__ G,
    float* __restrict__ out,
    unsigned int* cnt, float* hb, float* cb, float* rpp, float* wpl, int N)
{
  const int w = blockIdx.x;
  const int t = threadIdx.x;
  const int j = t >> 5;        // 0..15 local column
  const int l = t & 31;
  const int jg = w*JW + j;     // global h column

  __shared__ float hp[HH], cp[HH];
  __shared__ float ht[JW], zhh[JW], zc[JW], cwv[JW];
  __shared__ float rplog[104], e_ar[104], awlog[104], aw_n[104];
  __shared__ float part6[4][104];
  __shared__ float part2[4][128];
  __shared__ float memW[JW][104];
  __shared__ float Wrp_sl[JW][104];
  __shared__ float Wwp_sl[4][HH];
  __shared__ float scal[4];

  // register-resident column slices: Whh[:,jg], Wc_h[:,jg], Wrh[:,jg]
  float whh_r[16], wch_r[16], wrh_r[16];
#pragma unroll
  for (int i=0;i<16;i++){
    int k = i*32 + l;
    whh_r[i] = Whh[(size_t)k*HH + jg];
    wch_r[i] = Wc[(size_t)(II+k)*HH + jg];
    wrh_r[i] = Wrh[(size_t)k*HH + jg];
  }
  for (int idx=t; idx<JW*104; idx+=TSEQ){
    int kl = idx/104, m = idx - kl*104;
    int kgl = II + w*JW + kl;
    float v = 0.f;
    if (m < 100) v = Wrp[(size_t)kgl*100 + m];
    else if (m == 100) v = Wrg[kgl];
    Wrp_sl[kl][m] = v;
    memW[kl][m] = 0.f;   // same index space (JW x 104)
  }
  for (int idx=t; idx<4*HH; idx+=TSEQ){
    int ci = idx>>9, k = idx&511;
    int cg = ci*32 + w;
    float v = 0.f;
    if (cg < 100) v = Wwp[(size_t)(II+k)*100 + cg];
    else if (cg == 100) v = Wwg[II+k];
    Wwp_sl[ci][k] = v;
  }
  __syncthreads();

  // ---- phase 0: h0 = relu(B0), c0 = relu(A0); memW=0 => rW=0 regardless of ar/go ----
  if (t < JW) {
    float hv = fmaxf(0.f, bf2f(G[(size_t)0*GSTRIDE + w*JW + t]));
    float cv = fmaxf(0.f, bf2f(G[(size_t)0*GSTRIDE + 512 + w*JW + t]));
    ht[t] = hv;
    gstore(&hb[0*HH + w*JW + t], hv);
    gstore(&cb[0*HH + w*JW + t], cv);
    out[(size_t)0*HH + w*JW + t] = hv;
  }
  if (t < 4) {                 // wp logits for step 0 use h_{-1}=0 -> publish zeros
    int cg = t*32 + w;
    if (cg < 101) gstore(&wpl[0*104 + cg], 0.f);
  }
  __syncthreads();
  if (t < 404) {               // rp partials for step 1 from local h0 slice
    int m = t % 101, q = t / 101;
    float s = 0.f;
#pragma unroll
    for (int ii=0; ii<4; ii++) s += ht[q*4+ii] * Wrp_sl[q*4+ii][m];
    part6[q][m] = s;
  }
  __syncthreads();
  if (t < 101)
    gstore(&rpp[(size_t)(0*NWG + w)*104 + t], part6[0][t]+part6[1][t]+part6[2][t]+part6[3][t]);
  grid_barrier(cnt, NWG*1u);

  for (int step=1; step<N; ++step) {
    const int cur = step & 1, prv = cur ^ 1;
    // (1) read previous phase's publishes
    hp[t] = gload(&hb[prv*HH + t]);
    cp[t] = gload(&cb[prv*HH + t]);
    if (t < 404) {
      int m = t % 101, q = t / 101;
      const float* base = rpp + (size_t)(prv*NWG)*104 + m;
      float s0 = gload(&base[(q*8+0)*104]), s1 = gload(&base[(q*8+1)*104]);
      float s2 = gload(&base[(q*8+2)*104]), s3 = gload(&base[(q*8+3)*104]);
      float s4 = gload(&base[(q*8+4)*104]), s5 = gload(&base[(q*8+5)*104]);
      float s6 = gload(&base[(q*8+6)*104]), s7 = gload(&base[(q*8+7)*104]);
      part6[q][m] = ((s0+s1)+(s2+s3)) + ((s4+s5)+(s6+s7));
    } else if (t < 505) {
      awlog[t - 404] = gload(&wpl[prv*104 + (t-404)]);
    }
    __syncthreads();
    // (2) finalize logits (add x-parts from G)
    if (t < 101) {
      float s = part6[0][t]+part6[1][t]+part6[2][t]+part6[3][t];
      s += bf2f(G[(size_t)step*GSTRIDE + (t<100 ? 1024+t : 1224)]);
      rplog[t] = s;
    } else if (t >= 128 && t < 229) {
      int m = t - 128;
      awlog[m] += bf2f(G[(size_t)(step-1)*GSTRIDE + (m<100 ? 1124+m : 1225)]);
    }
    __syncthreads();
    // (3) register matvecs (Whh, Wc_h with h; Wrh with c) + wp partial dots
    float ph=0.f, pc=0.f, pw=0.f;
#pragma unroll
    for (int i=0;i<16;i++){
      float hv = hp[i*32+l], cv2 = cp[i*32+l];
      ph += whh_r[i]*hv;
      pc += wch_r[i]*hv;
      pw += wrh_r[i]*cv2;
    }
    ph = red32(ph); pc = red32(pc); pw = red32(pw);
    if (l == 0) { zhh[j]=ph; zc[j]=pc; cwv[j]=pw; }
    {
      int ci = t >> 7, li = t & 127;
      float s = 0.f;
#pragma unroll
      for (int ii=0; ii<4; ii++) s += hp[li + 128*ii] * Wwp_sl[ci][li + 128*ii];
      part2[ci][li] = s;
    }
    __syncthreads();
    // (4) softmaxes (waves 0,1) + wp logit publish (waves 2..5)
    {
      const int wv = t >> 6;
      if (wv == 0) {
        float v0 = rplog[t];
        float v1 = (t+64 < 100) ? rplog[t+64] : -1e30f;
        float mx = fmaxf(v0, v1);
#pragma unroll
        for (int off=32; off>=1; off>>=1) mx = fmaxf(mx, __shfl_xor(mx, off));
        float e0 = __expf(v0 - mx);
        float e1 = (t+64 < 100) ? __expf(v1 - mx) : 0.f;
        e_ar[t] = e0;
        if (t + 64 < 104) e_ar[t+64] = e1;
        float s = e0 + e1;
#pragma unroll
        for (int off=32; off>=1; off>>=1) s += __shfl_xor(s, off);
        if (t == 0) {
          float go = 1.f/(1.f+__expf(-rplog[100]));
          scal[0] = go / s;
        }
      } else if (wv == 1) {
        int m0 = t - 64;
        float v0 = awlog[m0];
        float v1 = (m0+64 < 100) ? awlog[m0+64] : -1e30f;
        float mx = fmaxf(v0, v1);
#pragma unroll
        for (int off=32; off>=1; off>>=1) mx = fmaxf(mx, __shfl_xor(mx, off));
        float e0 = __expf(v0 - mx);
        float e1 = (m0+64 < 100) ? __expf(v1 - mx) : 0.f;
        float s = e0 + e1;
#pragma unroll
        for (int off=32; off>=1; off>>=1) s += __shfl_xor(s, off);
        aw_n[m0] = e0 / s;
        if (m0+64 < 100) aw_n[m0+64] = e1 / s;
        if (m0 == 0) scal[1] = 1.f/(1.f+__expf(-awlog[100]));
      } else if (wv >= 2 && wv < 6) {
        int ci = wv - 2, ln = t & 63;
        float s = part2[ci][ln] + part2[ci][ln+64];
#pragma unroll
        for (int off=32; off>=1; off>>=1) s += __shfl_xor(s, off);
        if (ln == 0) {
          int cg = ci*32 + w;
          if (cg < 101) gstore(&wpl[cur*104 + cg], s);
        }
      }
    }
    __syncthreads();
    // (5) memW update (with aw_{t-1}, gw_{t-1}, cW_{t-1}) fused with rW accumulation
    {
      float gws = scal[1], gosum = scal[0], cwj = cwv[j];
      float rwp = 0.f;
#pragma unroll
      for (int q=0; q<4; q++){
        int m = l + 32*q;
        if (m < 100) {
          float a = aw_n[m];
          float mv = memW[j][m];
          mv = (1.f - a)*mv + gws*a*cwj;
          memW[j][m] = mv;
          rwp += e_ar[m]*mv;
        }
      }
      rwp = red32(rwp);
      if (l == 0) {
        float hv = fmaxf(0.f, bf2f(G[(size_t)step*GSTRIDE + jg]) + zhh[j] + gosum*rwp);
        float cv = fmaxf(0.f, bf2f(G[(size_t)step*GSTRIDE + 512 + jg]) + zc[j]);
        ht[j] = hv;
        out[(size_t)step*HH + jg] = hv;
        gstore(&hb[cur*HH + jg], hv);
        gstore(&cb[cur*HH + jg], cv);
      }
    }
    __syncthreads();
    // (6) rp partials for next step + barrier
    if (step + 1 < N) {
      if (t < 404) {
        int m = t % 101, q = t / 101;
        float s = 0.f;
#pragma unroll
        for (int ii=0; ii<4; ii++) s += ht[q*4+ii]*Wrp_sl[q*4+ii][m];
        part6[q][m] = s;
      }
      __syncthreads();
      if (t < 101)
        gstore(&rpp[(size_t)(cur*NWG + w)*104 + t], part6[0][t]+part6[1][t]+part6[2][t]+part6[3][t]);
      grid_barrier(cnt, NWG*(unsigned)(step+1));
    }
  }
}

extern "C" void kernel_launch(void* const* d_in, const int* in_sizes, int n_in,
                              void* d_out, int out_size, void* d_ws, size_t ws_size,
                              hipStream_t stream) {
  const float* X   = (const float*)d_in[0];
  const float* Wc  = (const float*)d_in[1];
  const float* bc  = (const float*)d_in[2];
  const float* Wwg = (const float*)d_in[3];
  const float* bwg = (const float*)d_in[4];
  const float* Wwp = (const float*)d_in[5];
  const float* bwp = (const float*)d_in[6];
  const float* Wrg = (const float*)d_in[7];
  const float* brg = (const float*)d_in[8];
  const float* Wrp = (const float*)d_in[9];
  const float* brp = (const float*)d_in[10];
  const float* Wxh = (const float*)d_in[11];
  const float* Wrh = (const float*)d_in[12];
  const float* Whh = (const float*)d_in[13];
  const float* bh  = (const float*)d_in[14];

  const int N = in_sizes[0] / II;   // 32768

  char* ws = (char*)d_ws;
  unsigned int* cnt = (unsigned int*)(ws + OFF_CNT);
  float* hb  = (float*)(ws + OFF_HBUF);
  float* cb  = (float*)(ws + OFF_CBUF);
  float* rpp = (float*)(ws + OFF_RPP);
  float* wpl = (float*)(ws + OFF_WPL);
  float* Wstack = (float*)(ws + OFF_WSTACK);
  __hip_bfloat16* G = (__hip_bfloat16*)(ws + OFF_G);
  float* out = (float*)d_out;

  // zero the barrier counter (ws is poisoned 0xAA before every timed launch)
  hipMemsetAsync(ws, 0, 1024, stream);

  pack_kernel<<<dim3(GSTRIDE/256, II+1), 256, 0, stream>>>(
      Wxh, bh, Wc, bc, Wrp, brp, Wwp, bwp, Wrg, brg, Wwg, bwg, Wstack);

  gemm_kernel<<<dim3(GSTRIDE/64, N/64), 256, 0, stream>>>(X, Wstack, G);

  seq_kernel<<<NWG, TSEQ, 0, stream>>>(
      Wc, Wwg, Wwp, Wrg, Wrp, Wrh, Whh, G, out,
      cnt, hb, cb, rpp, wpl, N);
}

// Round 3
// 139135.449 us; speedup vs baseline: 1.4274x; 1.2203x over previous
//
#include <hip/hip_runtime.h>
#include <hip/hip_bf16.h>

#define NWG 32
#define TSEQ 512
#define JW 16          // h-columns per WG
#define HH 512
#define II 1024
#define GSTRIDE 1280   // padded row stride of G (floats/bf16 elements)
#define RECF 160       // floats per publish record

// workspace byte offsets
#define OFF_FLAGS  0u                          // 32 flags, one per 64B line (2 KB)
#define OFF_REC    4096u                       // 2*32*160 f32 = 40 KB
#define OFF_WSTACK (1u<<20)                    // 1025*1280 f32 ~ 5.25 MB
#define OFF_G      (16u<<20)                   // N*1280 bf16 ~ 84 MB

__device__ __forceinline__ float bf2f(__hip_bfloat16 x){ return __bfloat162float(x); }

// cross-WG traffic: relaxed agent-scope (sc1, coherent at IF, no fences)
__device__ __forceinline__ void gstore(float* p, float v){
  __hip_atomic_store(p, v, __ATOMIC_RELAXED, __HIP_MEMORY_SCOPE_AGENT);
}
__device__ __forceinline__ float gload(const float* p){
  return __hip_atomic_load(p, __ATOMIC_RELAXED, __HIP_MEMORY_SCOPE_AGENT);
}

__device__ __forceinline__ float red32(float v){
  v += __shfl_xor(v, 16); v += __shfl_xor(v, 8); v += __shfl_xor(v, 4);
  v += __shfl_xor(v, 2);  v += __shfl_xor(v, 1);
  return v;
}

// ---------------- pack: Wstack[1025][1280], row 1024 = bias row ----------------
__global__ void pack_kernel(const float* __restrict__ Wxh, const float* __restrict__ bh,
                            const float* __restrict__ Wc,  const float* __restrict__ bc,
                            const float* __restrict__ Wrp, const float* __restrict__ brp,
                            const float* __restrict__ Wwp, const float* __restrict__ bwp,
                            const float* __restrict__ Wrg, const float* __restrict__ brg,
                            const float* __restrict__ Wwg, const float* __restrict__ bwg,
                            float* __restrict__ Wstack)
{
  int n = blockIdx.x*256 + threadIdx.x;
  int k = blockIdx.y;
  if (n >= GSTRIDE) return;
  float v = 0.f;
  if (k < II) {
    if (n < 512)       v = Wxh[k*512 + n];
    else if (n < 1024) v = Wc[k*512 + (n-512)];
    else if (n < 1124) v = Wrp[k*100 + (n-1024)];
    else if (n < 1224) v = Wwp[k*100 + (n-1124)];
    else if (n == 1224) v = Wrg[k];
    else if (n == 1225) v = Wwg[k];
  } else {
    if (n < 512)       v = bh[n];
    else if (n < 1024) v = bc[n-512];
    else if (n < 1124) v = brp[n-1024];
    else if (n < 1224) v = bwp[n-1124];
    else if (n == 1224) v = brg[0];
    else if (n == 1225) v = bwg[0];
  }
  Wstack[k*GSTRIDE + n] = v;
}

// ---------------- GEMM: G = X(32768x1024) @ Wstack(1024x1280) + bias, bf16 out ----------------
__global__ __launch_bounds__(256) void gemm_kernel(const float* __restrict__ X,
                                                   const float* __restrict__ Wstack,
                                                   __hip_bfloat16* __restrict__ G)
{
  __shared__ float As[16][68];
  __shared__ float Bs[16][64];
  const int tid = threadIdx.x;
  const int row0 = blockIdx.y*64, col0 = blockIdx.x*64;
  const int ty = tid>>4, tx = tid&15;
  const int amm = tid>>2, akk = (tid&3)<<2;
  const int bkk = tid>>4, bnn = (tid&15)<<2;
  float acc[4][4] = {{0.f}};
  for (int k0 = 0; k0 < II; k0 += 16) {
    float4 av = *(const float4*)(X + (size_t)(row0+amm)*II + k0 + akk);
    float4 bv = *(const float4*)(Wstack + (size_t)(k0+bkk)*GSTRIDE + col0 + bnn);
    __syncthreads();
    As[akk+0][amm]=av.x; As[akk+1][amm]=av.y; As[akk+2][amm]=av.z; As[akk+3][amm]=av.w;
    *(float4*)&Bs[bkk][bnn] = bv;
    __syncthreads();
#pragma unroll
    for (int kk=0; kk<16; kk++){
      float4 a = *(float4*)&As[kk][ty<<2];
      float4 b = *(float4*)&Bs[kk][tx<<2];
      acc[0][0] += a.x*b.x; acc[0][1] += a.x*b.y; acc[0][2] += a.x*b.z; acc[0][3] += a.x*b.w;
      acc[1][0] += a.y*b.x; acc[1][1] += a.y*b.y; acc[1][2] += a.y*b.z; acc[1][3] += a.y*b.w;
      acc[2][0] += a.z*b.x; acc[2][1] += a.z*b.y; acc[2][2] += a.z*b.z; acc[2][3] += a.z*b.w;
      acc[3][0] += a.w*b.x; acc[3][1] += a.w*b.y; acc[3][2] += a.w*b.z; acc[3][3] += a.w*b.w;
    }
  }
#pragma unroll
  for (int i2=0;i2<4;i2++){
    int r = row0 + (ty<<2) + i2;
#pragma unroll
    for (int j2=0;j2<4;j2++){
      int cidx = col0 + (tx<<2) + j2;
      float v = acc[i2][j2] + Wstack[(size_t)II*GSTRIDE + cidx];
      G[(size_t)r*GSTRIDE + cidx] = __float2bfloat16(v);
    }
  }
}

// ---------------- persistent sequential kernel ----------------
// mem eliminated: memW = mem @ Wrh (exact algebra). Cross-WG sync via per-WG
// sequence flags + contiguous data records (NO atomic RMW, no fences).
// Record layout (floats): [0..15]=h slice, [16..31]=c slice,
//                         [32..135]=rp partials (101 used), [136..139]=wp logits
__global__ __launch_bounds__(TSEQ) void seq_kernel(
    const float* __restrict__ Wc,  const float* __restrict__ Wwg,
    const float* __restrict__ Wwp, const float* __restrict__ Wrg,
    const float* __restrict__ Wrp, const float* __restrict__ Wrh,
    const float* __restrict__ Whh,
    const __hip_bfloat16* __restrict__ G,
    float* __restrict__ out,
    unsigned int* flags, float* rec, int N)
{
  const int w = blockIdx.x;
  const int t = threadIdx.x;
  const int j = t >> 5;        // 0..15 local column
  const int l = t & 31;
  const int jg = w*JW + j;     // global h column

  __shared__ float hp[HH], cp[HH];
  __shared__ float ht[JW], zhh[JW], zc[JW], cwv[JW];
  __shared__ float rplog[104], e_ar[104], awlog[104], aw_n[104];
  __shared__ float part6[4][104];
  __shared__ float part2[4][128];
  __shared__ float memW[JW][104];
  __shared__ float Wrp_sl[JW][104];
  __shared__ float Wwp_sl[4][HH];
  __shared__ float scal[4];

  float* myrec0 = rec + (size_t)(0*NWG + w)*RECF;
  float* myrec1 = rec + (size_t)(1*NWG + w)*RECF;

  // register-resident column slices: Whh[:,jg], Wc_h[:,jg], Wrh[:,jg]
  float whh_r[16], wch_r[16], wrh_r[16];
#pragma unroll
  for (int i=0;i<16;i++){
    int k = i*32 + l;
    whh_r[i] = Whh[(size_t)k*HH + jg];
    wch_r[i] = Wc[(size_t)(II+k)*HH + jg];
    wrh_r[i] = Wrh[(size_t)k*HH + jg];
  }
  for (int idx=t; idx<JW*104; idx+=TSEQ){
    int kl = idx/104, m = idx - kl*104;
    int kgl = II + w*JW + kl;
    float v = 0.f;
    if (m < 100) v = Wrp[(size_t)kgl*100 + m];
    else if (m == 100) v = Wrg[kgl];
    Wrp_sl[kl][m] = v;
    memW[kl][m] = 0.f;
  }
  for (int idx=t; idx<4*HH; idx+=TSEQ){
    int ci = idx>>9, k = idx&511;
    int cg = ci*32 + w;
    float v = 0.f;
    if (cg < 100) v = Wwp[(size_t)(II+k)*100 + cg];
    else if (cg == 100) v = Wwg[II+k];
    Wwp_sl[ci][k] = v;
  }
  __syncthreads();

  // ---- step 0: h0 = relu(G_xh[0]), c0 = relu(G_c[0]); memW=0 ----
  if (t < JW) {
    float hv = fmaxf(0.f, bf2f(G[(size_t)0*GSTRIDE + w*JW + t]));
    float cv = fmaxf(0.f, bf2f(G[(size_t)0*GSTRIDE + 512 + w*JW + t]));
    ht[t] = hv;
    gstore(&myrec0[t], hv);
    gstore(&myrec0[16+t], cv);
    out[(size_t)0*HH + w*JW + t] = hv;
  }
  if (t < 4) gstore(&myrec0[136+t], 0.f);   // wp logits of step 0 use h_{-1}=0
  __syncthreads();
  if (t < 404) {               // rp partials for step 1 from local h0 slice
    int m = t % 101, q = t / 101;
    float s = 0.f;
#pragma unroll
    for (int ii=0; ii<4; ii++) s += ht[q*4+ii] * Wrp_sl[q*4+ii][m];
    part6[q][m] = s;
  }
  __syncthreads();
  if (t < 101)
    gstore(&myrec0[32+t], part6[0][t]+part6[1][t]+part6[2][t]+part6[3][t]);
  __builtin_amdgcn_s_waitcnt(0);   // per-wave: drain record stores to coherence point
  __syncthreads();
  if (t == 0)
    __hip_atomic_store(&flags[w*16], 1u, __ATOMIC_RELAXED, __HIP_MEMORY_SCOPE_AGENT);

  for (int step=1; step<N; ++step) {
    const int cur = step & 1;
    const float* prec = rec + (size_t)((step&1)^1)*NWG*RECF;   // records of step-1
    float* crec = (cur ? myrec1 : myrec0);
    // (0) prefetch this step's G values into registers (hidden under the poll)
    float g_rp = 0.f, g_aw = 0.f, g_h = 0.f, g_c = 0.f;
    if (t <= 100) g_rp = bf2f(G[(size_t)step*GSTRIDE + (t<100 ? 1024+t : 1224)]);
    if (t >= 404 && t < 505) {
      int m = t - 404;
      g_aw = bf2f(G[(size_t)(step-1)*GSTRIDE + (m<100 ? 1124+m : 1225)]);
    }
    if (l == 0) {
      g_h = bf2f(G[(size_t)step*GSTRIDE + jg]);
      g_c = bf2f(G[(size_t)step*GSTRIDE + 512 + jg]);
    }
    // (0b) wait for all records of step-1 (per-WG flag poll, no RMW)
    if (t < 32) {
      const unsigned int* fp = flags + t*16;
      while (__hip_atomic_load(fp, __ATOMIC_RELAXED, __HIP_MEMORY_SCOPE_AGENT) < (unsigned)step) { }
    }
    __syncthreads();
    // (1) read records
    hp[t] = gload(&prec[(size_t)(t>>4)*RECF + (t&15)]);
    cp[t] = gload(&prec[(size_t)(t>>4)*RECF + 16 + (t&15)]);
    if (t < 404) {
      int m = t % 101, q = t / 101;
      const float* base = prec + (size_t)(q*8)*RECF + 32 + m;
      float s0 = gload(&base[0*RECF]), s1 = gload(&base[1*RECF]);
      float s2 = gload(&base[2*RECF]), s3 = gload(&base[3*RECF]);
      float s4 = gload(&base[4*RECF]), s5 = gload(&base[5*RECF]);
      float s6 = gload(&base[6*RECF]), s7 = gload(&base[7*RECF]);
      part6[q][m] = ((s0+s1)+(s2+s3)) + ((s4+s5)+(s6+s7));
    } else if (t < 505) {
      int m = t - 404;
      awlog[m] = gload(&prec[(size_t)(m&31)*RECF + 136 + (m>>5)]) + g_aw;
    }
    __syncthreads();
    // (2+3) finalize rp logits; register matvecs; wp partial dots
    if (t <= 100)
      rplog[t] = part6[0][t]+part6[1][t]+part6[2][t]+part6[3][t] + g_rp;
    float ph=0.f, pc=0.f, pw=0.f;
#pragma unroll
    for (int i=0;i<16;i++){
      float hv = hp[i*32+l], cv2 = cp[i*32+l];
      ph += whh_r[i]*hv;
      pc += wch_r[i]*hv;
      pw += wrh_r[i]*cv2;
    }
    ph = red32(ph); pc = red32(pc); pw = red32(pw);
    if (l == 0) { zhh[j]=ph; zc[j]=pc; cwv[j]=pw; }
    {
      int ci = t >> 7, li = t & 127;
      float s = 0.f;
#pragma unroll
      for (int ii=0; ii<4; ii++) s += hp[li + 128*ii] * Wwp_sl[ci][li + 128*ii];
      part2[ci][li] = s;
    }
    __syncthreads();
    // (4) softmaxes (waves 0,1) + wp logit publish (waves 2..5)
    {
      const int wv = t >> 6;
      if (wv == 0) {
        float v0 = rplog[t];
        float v1 = (t+64 < 100) ? rplog[t+64] : -1e30f;
        float mx = fmaxf(v0, v1);
#pragma unroll
        for (int off=32; off>=1; off>>=1) mx = fmaxf(mx, __shfl_xor(mx, off));
        float e0 = __expf(v0 - mx);
        float e1 = (t+64 < 100) ? __expf(v1 - mx) : 0.f;
        e_ar[t] = e0;
        if (t + 64 < 104) e_ar[t+64] = e1;
        float s = e0 + e1;
#pragma unroll
        for (int off=32; off>=1; off>>=1) s += __shfl_xor(s, off);
        if (t == 0) {
          float go = 1.f/(1.f+__expf(-rplog[100]));
          scal[0] = go / s;
        }
      } else if (wv == 1) {
        int m0 = t - 64;
        float v0 = awlog[m0];
        float v1 = (m0+64 < 100) ? awlog[m0+64] : -1e30f;
        float mx = fmaxf(v0, v1);
#pragma unroll
        for (int off=32; off>=1; off>>=1) mx = fmaxf(mx, __shfl_xor(mx, off));
        float e0 = __expf(v0 - mx);
        float e1 = (m0+64 < 100) ? __expf(v1 - mx) : 0.f;
        float s = e0 + e1;
#pragma unroll
        for (int off=32; off>=1; off>>=1) s += __shfl_xor(s, off);
        aw_n[m0] = e0 / s;
        if (m0+64 < 100) aw_n[m0+64] = e1 / s;
        if (m0 == 0) scal[1] = 1.f/(1.f+__expf(-awlog[100]));
      } else if (wv >= 2 && wv < 6) {
        int ci = wv - 2, ln = t & 63;
        float s = part2[ci][ln] + part2[ci][ln+64];
#pragma unroll
        for (int off=32; off>=1; off>>=1) s += __shfl_xor(s, off);
        if (ln == 0 && (ci*32 + w) < 101) gstore(&crec[136+ci], s);
      }
    }
    __syncthreads();
    // (5) memW update fused with rW accumulation; h/c finalize + publish
    {
      float gws = scal[1], gosum = scal[0], cwj = cwv[j];
      float rwp = 0.f;
#pragma unroll
      for (int q=0; q<4; q++){
        int m = l + 32*q;
        if (m < 100) {
          float a = aw_n[m];
          float mv = memW[j][m];
          mv = (1.f - a)*mv + gws*a*cwj;
          memW[j][m] = mv;
          rwp += e_ar[m]*mv;
        }
      }
      rwp = red32(rwp);
      if (l == 0) {
        float hv = fmaxf(0.f, g_h + zhh[j] + gosum*rwp);
        float cv = fmaxf(0.f, g_c + zc[j]);
        ht[j] = hv;
        out[(size_t)step*HH + jg] = hv;
        gstore(&crec[j], hv);
        gstore(&crec[16+j], cv);
      }
    }
    __syncthreads();
    // (6) rp partials for next step + flag release
    if (step + 1 < N) {
      if (t < 404) {
        int m = t % 101, q = t / 101;
        float s = 0.f;
#pragma unroll
        for (int ii=0; ii<4; ii++) s += ht[q*4+ii]*Wrp_sl[q*4+ii][m];
        part6[q][m] = s;
      }
      __syncthreads();
      if (t < 101)
        gstore(&crec[32+t], part6[0][t]+part6[1][t]+part6[2][t]+part6[3][t]);
      __builtin_amdgcn_s_waitcnt(0);   // per-wave drain of this step's record stores
      __syncthreads();
      if (t == 0)
        __hip_atomic_store(&flags[w*16], (unsigned)(step+1),
                           __ATOMIC_RELAXED, __HIP_MEMORY_SCOPE_AGENT);
    }
  }
}

extern "C" void kernel_launch(void* const* d_in, const int* in_sizes, int n_in,
                              void* d_out, int out_size, void* d_ws, size_t ws_size,
                              hipStream_t stream) {
  const float* X   = (const float*)d_in[0];
  const float* Wc  = (const float*)d_in[1];
  const float* bc  = (const float*)d_in[2];
  const float* Wwg = (const float*)d_in[3];
  const float* bwg = (const float*)d_in[4];
  const float* Wwp = (const float*)d_in[5];
  const float* bwp = (const float*)d_in[6];
  const float* Wrg = (const float*)d_in[7];
  const float* brg = (const float*)d_in[8];
  const float* Wrp = (const float*)d_in[9];
  const float* brp = (const float*)d_in[10];
  const float* Wxh = (const float*)d_in[11];
  const float* Wrh = (const float*)d_in[12];
  const float* Whh = (const float*)d_in[13];
  const float* bh  = (const float*)d_in[14];

  const int N = in_sizes[0] / II;   // 32768

  char* ws = (char*)d_ws;
  unsigned int* flags = (unsigned int*)(ws + OFF_FLAGS);
  float* rec = (float*)(ws + OFF_REC);
  float* Wstack = (float*)(ws + OFF_WSTACK);
  __hip_bfloat16* G = (__hip_bfloat16*)(ws + OFF_G);
  float* out = (float*)d_out;

  // zero flags (ws is poisoned 0xAA before every timed launch)
  hipMemsetAsync(ws, 0, 4096, stream);

  pack_kernel<<<dim3(GSTRIDE/256, II+1), 256, 0, stream>>>(
      Wxh, bh, Wc, bc, Wrp, brp, Wwp, bwp, Wrg, brg, Wwg, bwg, Wstack);

  gemm_kernel<<<dim3(GSTRIDE/64, N/64), 256, 0, stream>>>(X, Wstack, G);

  seq_kernel<<<NWG, TSEQ, 0, stream>>>(
      Wc, Wwg, Wwp, Wrg, Wrp, Wrh, Whh, G, out,
      flags, rec, N);
}

// Round 5
// 114904.797 us; speedup vs baseline: 1.7285x; 1.2109x over previous
//
#include <hip/hip_runtime.h>
#include <hip/hip_bf16.h>

#define NWG 32
#define TSEQ 512
#define JW 16          // h-columns per WG
#define HH 512
#define II 1024
#define GSTRIDE 1280   // padded row stride of G (floats/bf16 elements)
#define CHK 48         // 16B chunks per record (3 payload floats + tag each)
// payload index map: [0..15]=h, [16..31]=c, [32..132]=rp partials (101), [133..136]=wp logits

// workspace byte offsets
#define OFF_REC    4096u                       // 2*32*48*16B = 48 KB
#define OFF_WSTACK (1u<<20)                    // 1025*1280 f32 ~ 5.25 MB
#define OFF_G      (16u<<20)                   // N*1280 bf16 ~ 84 MB

typedef float fx4 __attribute__((ext_vector_type(4)));   // native vec: maps to v[4] tuple in asm

__device__ __forceinline__ float bf2f(__hip_bfloat16 x){ return __bfloat162float(x); }
__device__ __forceinline__ unsigned f2u(float x){ return __builtin_bit_cast(unsigned, x); }
__device__ __forceinline__ float u2f(unsigned x){ return __builtin_bit_cast(float, x); }

// 16B cache-bypassing (sc1: agent-coherent at Infinity Cache) load/store
__device__ __forceinline__ void ld_chunk3(const fx4* p0, const fx4* p1, const fx4* p2,
                                          fx4& a, fx4& b, fx4& c){
  asm volatile("global_load_dwordx4 %0, %3, off sc1\n\t"
               "global_load_dwordx4 %1, %4, off sc1\n\t"
               "global_load_dwordx4 %2, %5, off sc1\n\t"
               "s_waitcnt vmcnt(0)"
               : "=&v"(a), "=&v"(b), "=&v"(c)
               : "v"(p0), "v"(p1), "v"(p2) : "memory");
}
__device__ __forceinline__ void st_chunk(fx4* p, fx4 v){
  asm volatile("global_store_dwordx4 %0, %1, off sc1" :: "v"(p), "v"(v) : "memory");
}

__device__ __forceinline__ float red32(float v){
  v += __shfl_xor(v, 16); v += __shfl_xor(v, 8); v += __shfl_xor(v, 4);
  v += __shfl_xor(v, 2);  v += __shfl_xor(v, 1);
  return v;
}
__device__ __forceinline__ float redsum64(float v){
  v += __shfl_xor(v, 32); v += __shfl_xor(v, 16); v += __shfl_xor(v, 8);
  v += __shfl_xor(v, 4);  v += __shfl_xor(v, 2);  v += __shfl_xor(v, 1);
  return v;
}
__device__ __forceinline__ float redmax64(float v){
  v = fmaxf(v, __shfl_xor(v, 32)); v = fmaxf(v, __shfl_xor(v, 16));
  v = fmaxf(v, __shfl_xor(v, 8));  v = fmaxf(v, __shfl_xor(v, 4));
  v = fmaxf(v, __shfl_xor(v, 2));  v = fmaxf(v, __shfl_xor(v, 1));
  return v;
}

// ---------------- pack: Wstack[1025][1280], row 1024 = bias row ----------------
__global__ void pack_kernel(const float* __restrict__ Wxh, const float* __restrict__ bh,
                            const float* __restrict__ Wc,  const float* __restrict__ bc,
                            const float* __restrict__ Wrp, const float* __restrict__ brp,
                            const float* __restrict__ Wwp, const float* __restrict__ bwp,
                            const float* __restrict__ Wrg, const float* __restrict__ brg,
                            const float* __restrict__ Wwg, const float* __restrict__ bwg,
                            float* __restrict__ Wstack)
{
  int n = blockIdx.x*256 + threadIdx.x;
  int k = blockIdx.y;
  if (n >= GSTRIDE) return;
  float v = 0.f;
  if (k < II) {
    if (n < 512)       v = Wxh[k*512 + n];
    else if (n < 1024) v = Wc[k*512 + (n-512)];
    else if (n < 1124) v = Wrp[k*100 + (n-1024)];
    else if (n < 1224) v = Wwp[k*100 + (n-1124)];
    else if (n == 1224) v = Wrg[k];
    else if (n == 1225) v = Wwg[k];
  } else {
    if (n < 512)       v = bh[n];
    else if (n < 1024) v = bc[n-512];
    else if (n < 1124) v = brp[n-1024];
    else if (n < 1224) v = bwp[n-1124];
    else if (n == 1224) v = brg[0];
    else if (n == 1225) v = bwg[0];
  }
  Wstack[k*GSTRIDE + n] = v;
}

// ---------------- GEMM: G = X(32768x1024) @ Wstack(1024x1280) + bias, bf16 out ----------------
__global__ __launch_bounds__(256) void gemm_kernel(const float* __restrict__ X,
                                                   const float* __restrict__ Wstack,
                                                   __hip_bfloat16* __restrict__ G)
{
  __shared__ float As[16][68];
  __shared__ float Bs[16][64];
  const int tid = threadIdx.x;
  const int row0 = blockIdx.y*64, col0 = blockIdx.x*64;
  const int ty = tid>>4, tx = tid&15;
  const int amm = tid>>2, akk = (tid&3)<<2;
  const int bkk = tid>>4, bnn = (tid&15)<<2;
  float acc[4][4] = {{0.f}};
  for (int k0 = 0; k0 < II; k0 += 16) {
    float4 av = *(const float4*)(X + (size_t)(row0+amm)*II + k0 + akk);
    float4 bv = *(const float4*)(Wstack + (size_t)(k0+bkk)*GSTRIDE + col0 + bnn);
    __syncthreads();
    As[akk+0][amm]=av.x; As[akk+1][amm]=av.y; As[akk+2][amm]=av.z; As[akk+3][amm]=av.w;
    *(float4*)&Bs[bkk][bnn] = bv;
    __syncthreads();
#pragma unroll
    for (int kk=0; kk<16; kk++){
      float4 a = *(float4*)&As[kk][ty<<2];
      float4 b = *(float4*)&Bs[kk][tx<<2];
      acc[0][0] += a.x*b.x; acc[0][1] += a.x*b.y; acc[0][2] += a.x*b.z; acc[0][3] += a.x*b.w;
      acc[1][0] += a.y*b.x; acc[1][1] += a.y*b.y; acc[1][2] += a.y*b.z; acc[1][3] += a.y*b.w;
      acc[2][0] += a.z*b.x; acc[2][1] += a.z*b.y; acc[2][2] += a.z*b.z; acc[2][3] += a.z*b.w;
      acc[3][0] += a.w*b.x; acc[3][1] += a.w*b.y; acc[3][2] += a.w*b.z; acc[3][3] += a.w*b.w;
    }
  }
#pragma unroll
  for (int i2=0;i2<4;i2++){
    int r = row0 + (ty<<2) + i2;
#pragma unroll
    for (int j2=0;j2<4;j2++){
      int cidx = col0 + (tx<<2) + j2;
      float v = acc[i2][j2] + Wstack[(size_t)II*GSTRIDE + cidx];
      G[(size_t)r*GSTRIDE + cidx] = __float2bfloat16(v);
    }
  }
}

// ---------------- persistent sequential kernel ----------------
// mem eliminated: memW = mem @ Wrh (exact algebra). Cross-WG transport:
// tagged 16B chunks (3 payload + step tag), dwordx4 sc1 stores/loads —
// no flags, no fences, no drains. Consumers retry stale chunks.
__global__ __launch_bounds__(TSEQ) void seq_kernel(
    const float* __restrict__ Wc,  const float* __restrict__ Wwg,
    const float* __restrict__ Wwp, const float* __restrict__ Wrg,
    const float* __restrict__ Wrp, const float* __restrict__ Wrh,
    const float* __restrict__ Whh,
    const __hip_bfloat16* __restrict__ G,
    float* __restrict__ out,
    fx4* rec4, int N)
{
  const int w = blockIdx.x;
  const int t = threadIdx.x;
  const int j = t >> 5;        // 0..15 local column
  const int l = t & 31;
  const int jg = w*JW + j;     // global h column

  __shared__ fx4 raw4[NWG*CHK];        // staged records of step-1 (24 KB)
  __shared__ float pubbuf[144];        // this WG's outgoing payload
  __shared__ float ht[JW];
  __shared__ float e_ar[104], aw_n[104];
  __shared__ float part6[4][104];
  __shared__ float part2[4][128];
  __shared__ float memW[JW][104];
  __shared__ float Wrp_sl[JW][104];
  __shared__ float Wwp_sl[4][HH];
  __shared__ float scal_s[2];

  const float* rawf = (const float*)raw4;

  // register-resident column slices: Whh[:,jg], Wc_h[:,jg], Wrh[:,jg]
  float whh_r[16], wch_r[16], wrh_r[16];
#pragma unroll
  for (int i=0;i<16;i++){
    int k = i*32 + l;
    whh_r[i] = Whh[(size_t)k*HH + jg];
    wch_r[i] = Wc[(size_t)(II+k)*HH + jg];
    wrh_r[i] = Wrh[(size_t)k*HH + jg];
  }
  for (int idx=t; idx<JW*104; idx+=TSEQ){
    int kl = idx/104, m = idx - kl*104;
    int kgl = II + w*JW + kl;
    float v = 0.f;
    if (m < 100) v = Wrp[(size_t)kgl*100 + m];
    else if (m == 100) v = Wrg[kgl];
    Wrp_sl[kl][m] = v;
    memW[kl][m] = 0.f;
  }
  for (int idx=t; idx<4*HH; idx+=TSEQ){
    int ci = idx>>9, k = idx&511;
    int cg = ci*32 + w;
    float v = 0.f;
    if (cg < 100) v = Wwp[(size_t)(II+k)*100 + cg];
    else if (cg == 100) v = Wwg[II+k];
    Wwp_sl[ci][k] = v;
  }
  if (t < 144) pubbuf[t] = 0.f;
  __syncthreads();

  // ---- step 0: h0 = relu(G_xh[0]), c0 = relu(G_c[0]); memW=0; wp logits(h_-1=0)=0 ----
  if (t < JW) {
    float hv = fmaxf(0.f, bf2f(G[(size_t)0*GSTRIDE + w*JW + t]));
    float cv = fmaxf(0.f, bf2f(G[(size_t)0*GSTRIDE + 512 + w*JW + t]));
    ht[t] = hv;
    pubbuf[t] = hv;
    pubbuf[16+t] = cv;
    out[(size_t)0*HH + w*JW + t] = hv;
  }
  __syncthreads();
  if (t < 101) {
    float s = 0.f;
#pragma unroll
    for (int kl=0; kl<16; kl++) s += ht[kl]*Wrp_sl[kl][t];
    pubbuf[32+t] = s;
  }
  __syncthreads();
  if (t < CHK) {
    fx4 v;
    v.x = pubbuf[3*t]; v.y = pubbuf[3*t+1]; v.z = pubbuf[3*t+2];
    v.w = u2f(1u);
    st_chunk(rec4 + (size_t)w*CHK + t, v);
  }

  for (int step=1; step<N; ++step) {
    const unsigned tg = (unsigned)step;
    // (A) prefetch this step's G values into registers
    float g_rp0=0.f, g_rp1=0.f, g_aw0=0.f, g_aw1=0.f, g_h=0.f, g_c=0.f;
    {
      const __hip_bfloat16* Grow = G + (size_t)step*GSTRIDE;
      if (t < 64) {
        g_rp0 = bf2f(Grow[1024+t]);
        int m2 = t+64;
        g_rp1 = bf2f(Grow[m2==100 ? 1224 : 1024+m2]);
      } else if (t < 128) {
        const __hip_bfloat16* Gpr = G + (size_t)(step-1)*GSTRIDE;
        int u = t-64;
        g_aw0 = bf2f(Gpr[1124+u]);
        int m2 = u+64;
        g_aw1 = bf2f(Gpr[m2==100 ? 1225 : 1124+m2]);
      }
      if (l == 0) { g_h = bf2f(Grow[jg]); g_c = bf2f(Grow[512+jg]); }
    }
    // (B) bulk-load step-1 records (coalesced 16B chunks), retry until tags fresh
    {
      const fx4* prev4 = rec4 + (size_t)((step&1)^1)*NWG*CHK;
      const fx4 *p0 = prev4 + t, *p1 = prev4 + t + 512, *p2 = prev4 + t + 1024;
      fx4 a, b, c;
      ld_chunk3(p0, p1, p2, a, b, c);
      while (f2u(a.w) != tg || f2u(b.w) != tg || f2u(c.w) != tg)
        ld_chunk3(p0, p1, p2, a, b, c);
      raw4[t] = a; raw4[t+512] = b; raw4[t+1024] = c;
    }
    __syncthreads();   // b1: raw complete
    // (C) partial merges + register matvecs + wp partial dots (reads raw LDS)
    if (t < 404) {
      int m = t % 101, q = t / 101;
      int off = ((32+m)/3)*4 + (32+m)%3;
      const float* base = rawf + (size_t)q*8*192 + off;
      float s = ((base[0*192]+base[1*192])+(base[2*192]+base[3*192]))
              + ((base[4*192]+base[5*192])+(base[6*192]+base[7*192]));
      part6[q][m] = s;
    }
    float ph=0.f, pc=0.f, pw=0.f;
    {
      int l15 = l & 15, lh = l >> 4;
      int coh = (l15/3)*4 + l15%3;
      int coc = ((16+l15)/3)*4 + (16+l15)%3;
      const float* mh = rawf + lh*192;
#pragma unroll
      for (int i=0;i<16;i++){
        float hv = mh[384*i + coh];
        float cv2 = mh[384*i + coc];
        ph += whh_r[i]*hv;
        pc += wch_r[i]*hv;
        pw += wrh_r[i]*cv2;
      }
      ph = red32(ph); pc = red32(pc); pw = red32(pw);
    }
    {
      int ci = t >> 7, li = t & 127;
      float s = 0.f;
#pragma unroll
      for (int ii=0; ii<4; ii++){
        int k = li + 128*ii;
        float hv = rawf[(k>>4)*192 + ((k&15)/3)*4 + (k&15)%3];
        s += hv * Wwp_sl[ci][k];
      }
      part2[ci][li] = s;
    }
    __syncthreads();   // b2: part6/part2 ready
    // (D) wave0: ar softmax; wave1: aw softmax; waves2-5: wp logit reduce
    if (t < 64) {
      int u = t, m2 = u+64;
      float v0 = part6[0][u]+part6[1][u]+part6[2][u]+part6[3][u] + g_rp0;
      float v1 = (m2 <= 100) ? (part6[0][m2]+part6[1][m2]+part6[2][m2]+part6[3][m2] + g_rp1)
                             : -1e30f;
      float vs1 = (m2 < 100) ? v1 : -1e30f;
      float mx = redmax64(fmaxf(v0, vs1));
      float e0 = __expf(v0 - mx), e1 = __expf(vs1 - mx);
      e_ar[u] = e0;
      if (m2 < 104) e_ar[m2] = e1;
      float ssum = redsum64(e0 + e1);
      float r100 = __shfl(v1, 36);
      if (u == 0) scal_s[0] = (1.f/(1.f+__expf(-r100))) / ssum;
    } else if (t < 128) {
      int u = t-64, m2 = u+64;
      int wi0 = u&31, ci0 = u>>5, p0i = 133+ci0;
      float v0 = rawf[wi0*192 + (p0i/3)*4 + p0i%3] + g_aw0;
      float v1 = -1e30f;
      if (m2 <= 100) {
        int wi1 = m2&31, ci1 = m2>>5, p1i = 133+ci1;
        v1 = rawf[wi1*192 + (p1i/3)*4 + p1i%3] + g_aw1;
      }
      float vs1 = (m2 < 100) ? v1 : -1e30f;
      float mx = redmax64(fmaxf(v0, vs1));
      float e0 = __expf(v0 - mx), e1 = __expf(vs1 - mx);
      float ssum = redsum64(e0 + e1);
      aw_n[u] = e0 / ssum;
      if (m2 < 104) aw_n[m2] = e1 / ssum;
      float r100 = __shfl(v1, 36);
      if (u == 0) scal_s[1] = 1.f/(1.f+__expf(-r100));
    } else if (t < 384) {
      int wv = t >> 6;           // 2..5
      int ci = wv - 2, ln = t & 63;
      float s = part2[ci][ln] + part2[ci][ln+64];
      s = redsum64(s);
      if (ln == 0 && (ci*32 + w) < 101) pubbuf[133+ci] = s;
    }
    __syncthreads();   // b3: e_ar/aw_n/scal/pubbuf.wp ready
    // (E) memW update fused with rW accumulation; h/c finalize
    {
      float gws = scal_s[1], gos = scal_s[0];
      float rwp = 0.f;
#pragma unroll
      for (int q=0; q<4; q++){
        int m = l + 32*q;
        if (m < 100) {
          float a2 = aw_n[m];
          float mv = memW[j][m];
          mv = (1.f - a2)*mv + gws*a2*pw;
          memW[j][m] = mv;
          rwp += e_ar[m]*mv;
        }
      }
      rwp = red32(rwp);
      float hv = fmaxf(0.f, g_h + ph + gos*rwp);
      if (l == 0) {
        float cv = fmaxf(0.f, g_c + pc);
        ht[j] = hv;
        pubbuf[j] = hv;
        pubbuf[16+j] = cv;
        out[(size_t)step*HH + jg] = hv;
      }
    }
    if (step + 1 < N) {
      __syncthreads();   // b4: ht / pubbuf h,c ready
      // (F) rp partials for next step
      if (t < 101) {
        float s = 0.f;
#pragma unroll
        for (int kl=0; kl<16; kl++) s += ht[kl]*Wrp_sl[kl][t];
        pubbuf[32+t] = s;
      }
      __syncthreads();   // b5: pubbuf complete
      // (G) wave0 packs + fires tagged chunks; no drain, no flag
      if (t < CHK) {
        fx4 v;
        v.x = pubbuf[3*t]; v.y = pubbuf[3*t+1]; v.z = pubbuf[3*t+2];
        v.w = u2f((unsigned)(step+1));
        st_chunk(rec4 + (size_t)((step&1)*NWG + w)*CHK + t, v);
      }
    }
  }
}

extern "C" void kernel_launch(void* const* d_in, const int* in_sizes, int n_in,
                              void* d_out, int out_size, void* d_ws, size_t ws_size,
                              hipStream_t stream) {
  const float* X   = (const float*)d_in[0];
  const float* Wc  = (const float*)d_in[1];
  const float* bc  = (const float*)d_in[2];
  const float* Wwg = (const float*)d_in[3];
  const float* bwg = (const float*)d_in[4];
  const float* Wwp = (const float*)d_in[5];
  const float* bwp = (const float*)d_in[6];
  const float* Wrg = (const float*)d_in[7];
  const float* brg = (const float*)d_in[8];
  const float* Wrp = (const float*)d_in[9];
  const float* brp = (const float*)d_in[10];
  const float* Wxh = (const float*)d_in[11];
  const float* Wrh = (const float*)d_in[12];
  const float* Whh = (const float*)d_in[13];
  const float* bh  = (const float*)d_in[14];

  const int N = in_sizes[0] / II;   // 32768

  char* ws = (char*)d_ws;
  fx4* rec4 = (fx4*)(ws + OFF_REC);
  float* Wstack = (float*)(ws + OFF_WSTACK);
  __hip_bfloat16* G = (__hip_bfloat16*)(ws + OFF_G);
  float* out = (float*)d_out;

  pack_kernel<<<dim3(GSTRIDE/256, II+1), 256, 0, stream>>>(
      Wxh, bh, Wc, bc, Wrp, brp, Wwp, bwp, Wrg, brg, Wwg, bwg, Wstack);

  gemm_kernel<<<dim3(GSTRIDE/64, N/64), 256, 0, stream>>>(X, Wstack, G);

  seq_kernel<<<NWG, TSEQ, 0, stream>>>(
      Wc, Wwg, Wwp, Wrg, Wrp, Wrh, Whh, G, out,
      rec4, N);
}